// Round 4
// baseline (174.331 us; speedup 1.0000x reference)
//
#include <hip/hip_runtime.h>

// Detail_loss: loss = 0.25/(98*258*256) * sum_{n,h,w} ( |D[h][w+1]-D[h][w-1]| + |D[h+1][w]-D[h-1][w]| )
// where D[n,h,w] = sum_c (infer - ref)[n,c,h,w], zero outside [0,256)^2.
//
// R9: four structures (barrier-drain glds, reg window, 1-row-per-wave, counted
// vmcnt pipeline) all land at 55-60us. R7's counters prove the memory system
// serves 7.5 TB/s logical when given huge numbers of short independent load
// batches (451 MB in 60us); the 1x-traffic structures are ILP-starved because
// the compiler sinks VGPR loads (R6/R7: VGPR=36-40) and glds pipelines stall
// per-wave. The stencil's 3x row redundancy is the ONLY reason the saturating
// shape needed 3x traffic -> split it out:
//   pass1 compute_d: pure streaming map (6 indep loads -> 7 adds -> 1 store,
//     one float4 per thread, one-shot). Reads inputs exactly once, writes
//     25.7 MB D to workspace. Copy-bench shape -> expect 4-6 TB/s.
//   pass2 detail_stencil: 6272 waves x 4 output rows, 6 indep float4 row-loads
//     + register window + 2 shuffles/row. 37.6 MB logical, L2/L3-warm.
//   pass3: reduce 1568 partials.
// Fallback to single-kernel atomic (R7 structure, verified absmax 0) if the
// workspace can't hold D.

#define W 256
#define NIMG 98
#define CH_STRIDE 65536              // floats per channel
#define IMG_F4 16384                 // float4 per channel image
#define TOT_F4 (NIMG * IMG_F4)       // 1,605,632 float4 of D
#define P1_BLK (TOT_F4 / 256)        // 6272 one-shot blocks
#define NBAND2 (NIMG * 64)           // 6272 stencil waves (4 rows each)
#define P2_BLK (NBAND2 / 4)          // 1568 blocks
#define D_FLOATS (NIMG * 65536)      // 6,422,528
#define WS_NEED ((size_t)D_FLOATS * 4 + P2_BLK * 4)
#define SCALE (0.25f / 6472704.0f)   // 0.25/(98*258*256)

// ---------------- pass 1: D = channel-summed (x - y), pure stream ----------
__global__ __launch_bounds__(256) void compute_d(
    const float* __restrict__ x, const float* __restrict__ y,
    float4* __restrict__ D) {
  const int i = blockIdx.x * 256 + threadIdx.x;       // < TOT_F4, one-shot
  const int n = i >> 14;                              // image
  const int e = i & 16383;                            // float4 within image
  const float4* xb = (const float4*)x + (size_t)n * 3 * IMG_F4 + e;
  const float4* yb = (const float4*)y + (size_t)n * 3 * IMG_F4 + e;
  const float4 a0 = xb[0], a1 = xb[IMG_F4], a2 = xb[2 * IMG_F4];
  const float4 b0 = yb[0], b1 = yb[IMG_F4], b2 = yb[2 * IMG_F4];
  float4 d;
  d.x = (a0.x - b0.x) + (a1.x - b1.x) + (a2.x - b2.x);
  d.y = (a0.y - b0.y) + (a1.y - b1.y) + (a2.y - b2.y);
  d.z = (a0.z - b0.z) + (a1.z - b1.z) + (a2.z - b2.z);
  d.w = (a0.w - b0.w) + (a1.w - b1.w) + (a2.w - b2.w);
  D[i] = d;
}

// ---------------- pass 2: stencil on D -------------------------------------
// Wave handles 4 output rows: 6 independent row loads (1 float4/lane), then
// register-window math. Horizontal |D[w+1]-D[w-1]| via 2 shuffles (verified
// in R7, absmax 0); vertical |D[h+1]-D[h-1]| register-local.
__global__ __launch_bounds__(256) void detail_stencil(
    const float4* __restrict__ D, float* __restrict__ partial) {
  const int tid  = threadIdx.x;
  const int lane = tid & 63;
  const int wv   = tid >> 6;
  const int band = blockIdx.x * 4 + wv;     // 0..6271
  const int n     = band >> 6;
  const int strip = band & 63;
  const int r0    = strip * 4;              // first output row

  const float4* Db = D + (size_t)n * IMG_F4 + lane;   // row stride 64 float4

  const int gm = (r0 > 0) ? (r0 - 1) : 0;             // clamped halo rows
  const int gp = (r0 + 4 < 256) ? (r0 + 4) : 255;

  // 6 independent loads (row r0-1 .. r0+4).
  float4 d0 = Db[gm * 64];
  float4 d1 = Db[r0 * 64];
  float4 d2 = Db[(r0 + 1) * 64];
  float4 d3 = Db[(r0 + 2) * 64];
  float4 d4 = Db[(r0 + 3) * 64];
  float4 d5 = Db[gp * 64];

  // Mask clamped halo rows to the zero pad.
  const float m0 = (r0 > 0) ? 1.f : 0.f;
  const float m5 = (r0 + 4 < 256) ? 1.f : 0.f;
  d0.x *= m0; d0.y *= m0; d0.z *= m0; d0.w *= m0;
  d5.x *= m5; d5.y *= m5; d5.z *= m5; d5.w *= m5;

  float acc = 0.f;
  // Output row with window (Dm = row-1, Dc = row, Dp = row+1).
  #define ACCROW(Dm, Dc, Dp) do {                                     \
    float lm_ = __shfl_up((Dc).w, 1);                                 \
    if (lane == 0) lm_ = 0.f;                                         \
    float rr_ = __shfl_down((Dc).x, 1);                               \
    if (lane == 63) rr_ = 0.f;                                        \
    acc += fabsf((Dc).y - lm_) + fabsf((Dc).z - (Dc).x)              \
         + fabsf((Dc).w - (Dc).y) + fabsf(rr_ - (Dc).z);             \
    acc += fabsf((Dp).x - (Dm).x) + fabsf((Dp).y - (Dm).y)           \
         + fabsf((Dp).z - (Dm).z) + fabsf((Dp).w - (Dm).w);          \
  } while (0)

  ACCROW(d0, d1, d2);
  ACCROW(d1, d2, d3);
  ACCROW(d2, d3, d4);
  ACCROW(d3, d4, d5);
  #undef ACCROW

  // Wave reduce + block reduce.
  #pragma unroll
  for (int off = 32; off > 0; off >>= 1)
    acc += __shfl_down(acc, off, 64);
  __shared__ float ws[4];
  if (lane == 0) ws[wv] = acc;
  __syncthreads();
  if (tid == 0) partial[blockIdx.x] = ws[0] + ws[1] + ws[2] + ws[3];
}

// ---------------- pass 3: final reduce -------------------------------------
__global__ __launch_bounds__(256) void detail_stage2(
    const float* __restrict__ partial, float* __restrict__ out) {
  float acc = 0.f;
  for (int i = threadIdx.x; i < P2_BLK; i += 256) acc += partial[i];
  #pragma unroll
  for (int off = 32; off > 0; off >>= 1)
    acc += __shfl_down(acc, off, 64);
  __shared__ float ws[4];
  if ((threadIdx.x & 63) == 0) ws[threadIdx.x >> 6] = acc;
  __syncthreads();
  if (threadIdx.x == 0) out[0] = (ws[0] + ws[1] + ws[2] + ws[3]) * SCALE;
}

// ---------------- fallback: single-kernel atomic (R7 structure) ------------
struct Row6 { float4 a0, a1, a2, b0, b1, b2; };

__device__ __forceinline__ Row6 issue6(const float* __restrict__ xb,
                                       const float* __restrict__ yb, int ro) {
  Row6 r;
  r.a0 = *(const float4*)(xb + ro);
  r.a1 = *(const float4*)(xb + ro + CH_STRIDE);
  r.a2 = *(const float4*)(xb + ro + 2 * CH_STRIDE);
  r.b0 = *(const float4*)(yb + ro);
  r.b1 = *(const float4*)(yb + ro + CH_STRIDE);
  r.b2 = *(const float4*)(yb + ro + 2 * CH_STRIDE);
  return r;
}

__device__ __forceinline__ float4 combine(const Row6& r, float m) {
  float4 d;
  d.x = m * ((r.a0.x - r.b0.x) + (r.a1.x - r.b1.x) + (r.a2.x - r.b2.x));
  d.y = m * ((r.a0.y - r.b0.y) + (r.a1.y - r.b1.y) + (r.a2.y - r.b2.y));
  d.z = m * ((r.a0.z - r.b0.z) + (r.a1.z - r.b1.z) + (r.a2.z - r.b2.z));
  d.w = m * ((r.a0.w - r.b0.w) + (r.a1.w - r.b1.w) + (r.a2.w - r.b2.w));
  return d;
}

__global__ __launch_bounds__(256) void detail_atomic(
    const float* __restrict__ x, const float* __restrict__ y,
    float* __restrict__ out) {
  const int tid  = threadIdx.x;
  const int lane = tid & 63;
  const int wv   = tid >> 6;
  const int task = blockIdx.x * 4 + wv;     // row task, 0..25087
  const int n = task >> 8;
  const int h = task & 255;

  const float* xb = x + (size_t)n * 3 * CH_STRIDE + (lane << 2);
  const float* yb = y + (size_t)n * 3 * CH_STRIDE + (lane << 2);
  const int hm = (h > 0) ? h - 1 : 0;
  const int hp = (h < 255) ? h + 1 : 255;

  Row6 rm = issue6(xb, yb, hm * W);
  Row6 rc = issue6(xb, yb, h * W);
  Row6 rp = issue6(xb, yb, hp * W);
  float4 dm = combine(rm, (h > 0) ? 1.f : 0.f);
  float4 dc = combine(rc, 1.f);
  float4 dp = combine(rp, (h < 255) ? 1.f : 0.f);

  float lm = __shfl_up(dc.w, 1);
  if (lane == 0) lm = 0.f;
  float rr = __shfl_down(dc.x, 1);
  if (lane == 63) rr = 0.f;
  float acc = fabsf(dc.y - lm) + fabsf(dc.z - dc.x)
            + fabsf(dc.w - dc.y) + fabsf(rr - dc.z);
  acc += fabsf(dp.x - dm.x) + fabsf(dp.y - dm.y)
       + fabsf(dp.z - dm.z) + fabsf(dp.w - dm.w);

  #pragma unroll
  for (int off = 32; off > 0; off >>= 1)
    acc += __shfl_down(acc, off, 64);
  __shared__ float ws[4];
  if (lane == 0) ws[wv] = acc;
  __syncthreads();
  if (tid == 0)
    atomicAdd(out, (ws[0] + ws[1] + ws[2] + ws[3]) * SCALE);
}

extern "C" void kernel_launch(void* const* d_in, const int* in_sizes, int n_in,
                              void* d_out, int out_size, void* d_ws, size_t ws_size,
                              hipStream_t stream) {
  const float* infer = (const float*)d_in[0];
  const float* ref   = (const float*)d_in[1];
  float* out = (float*)d_out;

  if (ws_size >= WS_NEED) {
    float4* D      = (float4*)d_ws;
    float* partial = (float*)d_ws + D_FLOATS;
    compute_d<<<P1_BLK, 256, 0, stream>>>(infer, ref, D);
    detail_stencil<<<P2_BLK, 256, 0, stream>>>(D, partial);
    detail_stage2<<<1, 256, 0, stream>>>(partial, out);
  } else {
    hipMemsetAsync(out, 0, sizeof(float), stream);
    detail_atomic<<<25088 / 4, 256, 0, stream>>>(infer, ref, out);
  }
}